// Round 10
// baseline (34.702 us; speedup 1.0000x reference)
//
#include <hip/hip_runtime.h>

#define S_DIM 64
#define B_DIM 256
#define D_DIM 1024
#define BS (B_DIM * S_DIM)        /* 16384 */
#define LP (B_DIM * (S_DIM - 1)) /* 16128 */
#define NBP 128                   /* blocks in pair_kernel */
#define PSTR 8                    /* partials per row (2 halves x 4 quarters) */

__device__ __forceinline__ float dot4(float4 a, float4 b) {
  return a.x * b.x + a.y * b.y + a.z * b.z + a.w * b.w;
}

// DPP row_ror add (pure VALU): after 4 steps every lane holds its 16-lane
// row's sum. No readlane finish -- we store 4 quarter-partials per wave.
template <int CTRL>
__device__ __forceinline__ float dpp_add(float v) {
  int r = __builtin_amdgcn_update_dpp(__float_as_int(v), __float_as_int(v),
                                      CTRL, 0xF, 0xF, false);
  return v + __int_as_float(r);
}

__device__ __forceinline__ float red16(float v) {
  v = dpp_add<0x128>(v);  // row_ror:8
  v = dpp_add<0x124>(v);  // row_ror:4
  v = dpp_add<0x122>(v);  // row_ror:2
  v = dpp_add<0x121>(v);  // row_ror:1
  return v;
}

// Full 64-lane reduce (tail reductions only).
__device__ __forceinline__ float red64_uni(float v) {
  v = red16(v);
  float r = __int_as_float(__builtin_amdgcn_readlane(__float_as_int(v), 0));
  r += __int_as_float(__builtin_amdgcn_readlane(__float_as_int(v), 16));
  r += __int_as_float(__builtin_amdgcn_readlane(__float_as_int(v), 32));
  r += __int_as_float(__builtin_amdgcn_readlane(__float_as_int(v), 48));
  return r;
}

// ws layout (floats):
//   nl2p[8BS] | nt2p[8BS] | ltp[8BS] | ajlp[8BS] | ajtp[8BS]   (stats)
//   partial[6*NBP]                                              (+40BS)
//   cnt (int)                                                   (+40BS+6*NBP)
#define WS_PART (40 * BS)
#define WS_CNT  (WS_PART + 6 * NBP)

// ---------------------------------------------------------------------------
// Kernel 1: per-row reductions. Autonomous waves (no LDS, no barrier): one
// wave per {batch, 2-row chunk, d-half}. MASK-GATED loads. All mask bytes
// (both layout candidates) issue IN PARALLEL with the layout-detection read,
// so the critical path is one memory latency, not two. Truncated reduction:
// 4 quarter-partials per half-row stored by lanes 0/16/32/48.
// ---------------------------------------------------------------------------
__global__ __launch_bounds__(256) void row_stats_kernel(
    const float* __restrict__ logits, const float* __restrict__ tgt,
    const unsigned char* __restrict__ mask, float* __restrict__ ws) {
  const int tid = threadIdx.x;
  const int lane = tid & 63;

  if (blockIdx.x == 0 && tid == 0)
    reinterpret_cast<int*>(ws + WS_CNT)[0] = 0;  // arm pair_kernel's counter

  int bid = blockIdx.x;
  bid = (bid & 7) * 512 + (bid >> 3);      // XCD swizzle, bijective (4096%8==0)
  const int gw = (bid << 2) | (tid >> 6);  // 0..16383
  const int h  = gw & 1;                   // d-half
  const int s0 = ((gw >> 1) & 31) << 1;    // 0,2,...,62
  const int b  = gw >> 6;                  // batch

  float* nl2p = ws;
  float* nt2p = ws + 8 * BS;
  float* ltp  = ws + 16 * BS;
  float* ajlp = ws + 24 * BS;
  float* ajtp = ws + 32 * BS;

  // Issue ALL mask reads up front (layout detection + both layout candidates
  // for the 3 row-validity bytes); select after the ballot.
  const int ib = b * S_DIM;
  const int sp = (s0 > 0) ? s0 - 1 : s0;
  const unsigned char mA0 = mask[ib + s0];
  const unsigned char mB0 = mask[(ib + s0) << 2];
  const unsigned char mA1 = mask[ib + s0 + 1];
  const unsigned char mB1 = mask[(ib + s0 + 1) << 2];
  const unsigned char mAp = mask[ib + sp];
  const unsigned char mBp = mask[(ib + sp) << 2];
  uchar4 det = reinterpret_cast<const uchar4*>(mask)[lane];
  const bool isbyte = __ballot((det.y | det.z | det.w) != 0) != 0ull;

  const bool v0 = (isbyte ? mA0 : mB0) == 0;
  const bool v1 = (isbyte ? mA1 : mB1) == 0;
  const bool vp = (s0 > 0) && ((isbyte ? mAp : mBp) == 0);
  const bool needP  = v0 && vp;   // pair (s0-1, s0)
  const bool needP1 = v0 && v1;   // pair (s0, s0+1)

  const int fo = h * 128 + lane;  // float4 index within row (+64 for j=1)

  float4 R[4], N[4], P[4];  // rows s0, s0+1, s0-1; [0..1]=logits, [2..3]=tgt

  auto ldrow = [&](int s, float4* dst) {
    const float4* Lp = reinterpret_cast<const float4*>(
        logits + ((size_t)s * B_DIM + b) * D_DIM);
    const float4* Tp = reinterpret_cast<const float4*>(
        tgt + ((size_t)s * B_DIM + b) * D_DIM);
    dst[0] = Lp[fo];
    dst[1] = Lp[fo + 64];
    dst[2] = Tp[fo];
    dst[3] = Tp[fo + 64];
  };

  if (v0) ldrow(s0, R);
  if (v1) ldrow(s0 + 1, N);
  if (needP) ldrow(s0 - 1, P);

  float a0 = 0.f, a1 = 0.f, a2 = 0.f, a3 = 0.f, a4 = 0.f;
  float b0 = 0.f, b1 = 0.f, b2 = 0.f, b3 = 0.f, b4 = 0.f;
  if (v0) {
    a0 = dot4(R[0], R[0]) + dot4(R[1], R[1]);
    a1 = dot4(R[2], R[2]) + dot4(R[3], R[3]);
    a2 = dot4(R[0], R[2]) + dot4(R[1], R[3]);
  }
  if (needP) {
    a3 = dot4(R[0], P[0]) + dot4(R[1], P[1]);  // aj[s0-1] logits
    a4 = dot4(R[2], P[2]) + dot4(R[3], P[3]);  // aj[s0-1] tgt
  }
  if (v1) {
    b0 = dot4(N[0], N[0]) + dot4(N[1], N[1]);
    b1 = dot4(N[2], N[2]) + dot4(N[3], N[3]);
    b2 = dot4(N[0], N[2]) + dot4(N[1], N[3]);
  }
  if (needP1) {
    b3 = dot4(N[0], R[0]) + dot4(N[1], R[1]);  // aj[s0] logits
    b4 = dot4(N[2], R[2]) + dot4(N[3], R[3]);  // aj[s0] tgt
  }

  if (v0) { a0 = red16(a0); a1 = red16(a1); a2 = red16(a2); }
  if (needP) { a3 = red16(a3); a4 = red16(a4); }
  if (v1) { b0 = red16(b0); b1 = red16(b1); b2 = red16(b2); }
  if (needP1) { b3 = red16(b3); b4 = red16(b4); }

  if ((lane & 15) == 0) {  // lanes 0,16,32,48: quarter-partial leaders
    const int q = lane >> 4;
    const int i = b * S_DIM + s0;
    const int o = PSTR * i + h * 4 + q;
    if (v0) { nl2p[o] = a0; nt2p[o] = a1; ltp[o] = a2; }
    if (needP) { ajlp[o - PSTR] = a3; ajtp[o - PSTR] = a4; }
    if (v1) {
      nl2p[o + PSTR] = b0; nt2p[o + PSTR] = b1; ltp[o + PSTR] = b2;
    }
    if (needP1) { ajlp[o] = b3; ajtp[o] = b4; }
  }
}

// Sum the 8 partials of one row: two float4 loads.
__device__ __forceinline__ float ld8(const float* p, int i) {
  const float4* q4 = reinterpret_cast<const float4*>(p) + 2 * i;
  float4 x = q4[0], y = q4[1];
  return ((x.x + x.y) + (x.z + x.w)) + ((y.x + y.y) + (y.z + y.w));
}

// ---------------------------------------------------------------------------
// Kernel 2: mask-weighted row sums + pair delta/dd terms, FUSED with the
// final combine via a last-block-done protocol (device-scope counter; the
// last block re-reads all partials with agent-scope atomic loads -- safe
// across non-coherent XCD L2s -- and writes the scalar loss).
// ---------------------------------------------------------------------------
__global__ __launch_bounds__(128) void pair_kernel(
    const unsigned char* __restrict__ mask, float* __restrict__ ws,
    float* __restrict__ out) {
  const float* nl2p = ws;
  const float* nt2p = ws + 8 * BS;
  const float* ltp  = ws + 16 * BS;
  const float* ajlp = ws + 24 * BS;
  const float* ajtp = ws + 32 * BS;
  float* partial = ws + WS_PART;
  int* cnt = reinterpret_cast<int*>(ws + WS_CNT);

  __shared__ unsigned long long vb[16];
  __shared__ float psum[6][2];
  __shared__ int s_flag;

  const int tid = threadIdx.x;
  const int w = tid >> 6, lane = tid & 63;

  if (tid == 0) s_flag = 0;
  __syncthreads();
  int any = 0;
  for (int i = tid; i < 1024; i += 128)
    if ((i & 3) == 1 && mask[i]) any = 1;
  if (any) s_flag = 1;
  __syncthreads();
  const bool isbyte = (s_flag != 0);

  int B0 = (blockIdx.x * 128) / 63;
  if (B0 > B_DIM - 16) B0 = B_DIM - 16;

#pragma unroll
  for (int k = 0; k < 8; ++k) {
    const int q = k * 2 + w;
    const int g2 = (B0 + q) * 64 + lane;
    bool val = mask[isbyte ? g2 : (g2 << 2)] == 0;
    unsigned long long bal = __ballot(val);
    if (lane == 0) vb[q] = bal;
  }
  __syncthreads();

  const int g = blockIdx.x * 128 + tid;  // row id and pair id

  float nv = 0.f, mse = 0.f, coss = 0.f, dsum = 0.f, ddsum = 0.f, cntf = 0.f;

  // Row terms.
  if (mask[isbyte ? g : (g << 2)] == 0) {
    float A = ld8(nl2p, g), Q = ld8(nt2p, g), Cc = ld8(ltp, g);
    nv = 1.f;
    mse = A + Q - 2.f * Cc;
    coss = 1.f - Cc / (fmaxf(sqrtf(A), 1e-8f) * fmaxf(sqrtf(Q), 1e-8f));
  }

  // Pair terms.
  if (g < LP) {
    const int b = g / 63;
    const int s = g - b * 63;
    const unsigned long long pbb = vb[b - B0] & (vb[b - B0] >> 1);
    if ((pbb >> s) & 1ull) {
      const int i0 = b * S_DIM + s;
      float dl = ld8(ajlp, i0) / (fmaxf(sqrtf(ld8(nl2p, i0)), 1e-6f) *
                                  fmaxf(sqrtf(ld8(nl2p, i0 + 1)), 1e-6f));
      float dt = ld8(ajtp, i0) / (fmaxf(sqrtf(ld8(nt2p, i0)), 1e-6f) *
                                  fmaxf(sqrtf(ld8(nt2p, i0 + 1)), 1e-6f));
      float wv = dl - dt;
      dsum = wv * wv;
      cntf = 1.f;

      // Next valid pair: bit scan through the LDS window.
      int bq = b, sq = -1;
      bool found = false, fellback = false;
      unsigned long long cur = pbb & (~0ull << (s + 1));
      while (true) {
        if (cur) { sq = __builtin_ctzll(cur); found = true; break; }
        ++bq;
        if (bq >= B_DIM) break;
        if (bq - B0 < 16) {
          cur = vb[bq - B0] & (vb[bq - B0] >> 1);
        } else {
          fellback = true;
          break;
        }
      }
      if (fellback) {  // correctness fallback; ~never taken for random masks
        while (bq < B_DIM && !found) {
          for (int s2 = 0; s2 < 63; ++s2) {
            int r0 = bq * S_DIM + s2;
            bool q1 = mask[isbyte ? r0 : (r0 << 2)] == 0;
            bool q2 = mask[isbyte ? (r0 + 1) : ((r0 + 1) << 2)] == 0;
            if (q1 && q2) { sq = s2; found = true; break; }
          }
          if (!found) ++bq;
        }
      }
      if (found) {
        const int j0 = bq * S_DIM + sq;
        float dlq = ld8(ajlp, j0) / (fmaxf(sqrtf(ld8(nl2p, j0)), 1e-6f) *
                                     fmaxf(sqrtf(ld8(nl2p, j0 + 1)), 1e-6f));
        float dtq = ld8(ajtp, j0) / (fmaxf(sqrtf(ld8(nt2p, j0)), 1e-6f) *
                                     fmaxf(sqrtf(ld8(nt2p, j0 + 1)), 1e-6f));
        float ddl = (dlq - dl) / ((dl != 0.f) ? dl : 1e-6f);
        float ddt = (dtq - dt) / ((dt != 0.f) ? dt : 1e-6f);
        float u = ddl - ddt;
        ddsum = u * u;
      }
    }
  }

  float vals[6] = {nv, mse, coss, dsum, ddsum, cntf};
#pragma unroll
  for (int k2 = 0; k2 < 6; ++k2) {
    float v = red64_uni(vals[k2]);
    if (lane == 0) psum[k2][w] = v;
  }
  __syncthreads();
  if (tid == 0) {
#pragma unroll
    for (int k2 = 0; k2 < 6; ++k2)
      partial[k2 * NBP + blockIdx.x] = psum[k2][0] + psum[k2][1];
  }

  // -------- last-block-done final combine --------
  __threadfence();  // device-scope release of this block's partials
  __shared__ int s_last;
  if (tid == 0) {
    int prev = __hip_atomic_fetch_add(cnt, 1, __ATOMIC_ACQ_REL,
                                      __HIP_MEMORY_SCOPE_AGENT);
    s_last = (prev == NBP - 1);
  }
  __syncthreads();
  if (!s_last) return;

  // Last block: reduce all partials (agent-scope loads bypass stale L2).
  float acc[6];
#pragma unroll
  for (int k2 = 0; k2 < 6; ++k2) {
    float v = __hip_atomic_load(&partial[k2 * NBP + tid], __ATOMIC_RELAXED,
                                __HIP_MEMORY_SCOPE_AGENT);
    v = red64_uni(v);
    if (lane == 0) psum[k2][w] = v;
  }
  __syncthreads();
  if (tid == 0) {
    float nvT  = psum[0][0] + psum[0][1];
    float mseT = psum[1][0] + psum[1][1];
    float cosT = psum[2][0] + psum[2][1];
    float dT   = psum[3][0] + psum[3][1];
    float ddT  = psum[4][0] + psum[4][1];
    float cT   = psum[5][0] + psum[5][1];
    out[0] = mseT / (nvT * (float)D_DIM) + cosT / nvT +
             dT / fmaxf(cT, 1.f) + (ddT / fmaxf(cT - 1.f, 1.f)) * 0.01f;
  }
}

extern "C" void kernel_launch(void* const* d_in, const int* in_sizes, int n_in,
                              void* d_out, int out_size, void* d_ws, size_t ws_size,
                              hipStream_t stream) {
  const float* logits = (const float*)d_in[0];
  const float* tgt    = (const float*)d_in[1];
  const unsigned char* mask = (const unsigned char*)d_in[2];
  float* out = (float*)d_out;
  float* ws  = (float*)d_ws;

  row_stats_kernel<<<dim3(4096), dim3(256), 0, stream>>>(logits, tgt, mask, ws);
  pair_kernel<<<dim3(NBP), dim3(128), 0, stream>>>(mask, ws, out);
}

// Round 11
// 29.284 us; speedup vs baseline: 1.1850x; 1.1850x over previous
//
#include <hip/hip_runtime.h>

#define S_DIM 64
#define B_DIM 256
#define D_DIM 1024
#define BS (B_DIM * S_DIM)        /* 16384 */
#define LP (B_DIM * (S_DIM - 1)) /* 16128 */
#define NBP 128                   /* blocks in pair_kernel */

__device__ __forceinline__ float dot4(float4 a, float4 b) {
  return a.x * b.x + a.y * b.y + a.z * b.z + a.w * b.w;
}

// DPP row_ror add (pure VALU, no LDS) + readlane finish.
template <int CTRL>
__device__ __forceinline__ float dpp_add(float v) {
  int r = __builtin_amdgcn_update_dpp(__float_as_int(v), __float_as_int(v),
                                      CTRL, 0xF, 0xF, false);
  return v + __int_as_float(r);
}

__device__ __forceinline__ float red64_uni(float v) {
  v = dpp_add<0x128>(v);  // row_ror:8
  v = dpp_add<0x124>(v);  // row_ror:4
  v = dpp_add<0x122>(v);  // row_ror:2
  v = dpp_add<0x121>(v);  // row_ror:1
  float r = __int_as_float(__builtin_amdgcn_readlane(__float_as_int(v), 0));
  r += __int_as_float(__builtin_amdgcn_readlane(__float_as_int(v), 16));
  r += __int_as_float(__builtin_amdgcn_readlane(__float_as_int(v), 32));
  r += __int_as_float(__builtin_amdgcn_readlane(__float_as_int(v), 48));
  return r;
}

// ---------------------------------------------------------------------------
// Kernel 1: per-row reductions, D split across two waves per row (h=0,1).
// Block = 512 threads = 8 waves = 4 s-chunks x 2 halves covering 8 rows of
// one batch. MASK-GATED: a row is loaded/reduced ONLY if valid (invalid rows
// contribute to no loss term), cutting logical traffic ~2x. Boundary rows
// shared through LDS (one barrier). All mask branches are wave-uniform.
// ws layout (floats): nl2p[2BS] | nt2p[2BS] | ltp[2BS] | ajlp[2BS] | ajtp[2BS]
//                     | partial[6*NBP]
// Half-partials at [2*rowid + h]; pair_kernel sums the halves. Entries for
// invalid rows/pairs are never written NOR read.
// ---------------------------------------------------------------------------
__global__ __launch_bounds__(512) void row_stats_kernel(
    const float* __restrict__ logits, const float* __restrict__ tgt,
    const unsigned char* __restrict__ mask, float* __restrict__ ws) {
  const int tid = threadIdx.x;
  const int lane = tid & 63;
  const int wv = tid >> 6;            // wave in block, 0..7
  int bid = blockIdx.x;
  bid = (bid & 7) * 256 + (bid >> 3); // XCD swizzle, bijective (2048 % 8 == 0)
  const int b  = bid >> 3;            // batch
  const int r0 = (bid & 7) << 3;      // block row base: 0,8,...,56
  const int k  = wv >> 1;             // chunk in block, 0..3
  const int h  = wv & 1;              // d-half
  const int s0 = r0 + (k << 1);       // first row of this wave's chunk

  float* nl2p = ws;
  float* nt2p = ws + 2 * BS;
  float* ltp  = ws + 4 * BS;
  float* ajlp = ws + 6 * BS;
  float* ajtp = ws + 8 * BS;

  // Mask layout detection (byte vs int32 storage), wave-local: bytes at
  // offset %4 != 0 are nonzero only for byte layout (192 random bytes).
  uchar4 det = reinterpret_cast<const uchar4*>(mask)[lane];
  const bool isbyte = __ballot((det.y | det.z | det.w) != 0) != 0ull;
  auto mvalid = [&](int s) -> bool {
    const int idx = b * S_DIM + s;
    return mask[isbyte ? idx : (idx << 2)] == 0;
  };
  const bool v0 = mvalid(s0);
  const bool v1 = mvalid(s0 + 1);
  const bool vp = (s0 > 0) && mvalid(s0 - 1);
  const bool needP  = v0 && vp;   // pair (s0-1, s0)
  const bool needP1 = v0 && v1;   // pair (s0, s0+1)

  const int fo = h * 128 + lane;  // float4 index within row (+64 for j=1)

  // Per-wave LDS export of row s0+1: [0..127]=logits half, [128..255]=tgt half
  __shared__ float4 lds[8][256];

  float4 R[4], N[4], P[4];  // rows s0, s0+1, s0-1; [0..1]=logits, [2..3]=tgt

  auto ldrow = [&](int s, float4* dst) {
    const float4* Lp = reinterpret_cast<const float4*>(
        logits + ((size_t)s * B_DIM + b) * D_DIM);
    const float4* Tp = reinterpret_cast<const float4*>(
        tgt + ((size_t)s * B_DIM + b) * D_DIM);
    dst[0] = Lp[fo];
    dst[1] = Lp[fo + 64];
    dst[2] = Tp[fo];
    dst[3] = Tp[fo + 64];
  };

  if (v0) ldrow(s0, R);
  if (v1) ldrow(s0 + 1, N);
  if (k == 0 && needP) ldrow(s0 - 1, P);  // first chunk: prev from global

  if (v1) {  // export row s0+1 for the next chunk's pair (s0+1, s0+2)
    lds[wv][lane]       = N[0];
    lds[wv][lane + 64]  = N[1];
    lds[wv][lane + 128] = N[2];
    lds[wv][lane + 192] = N[3];
  }

  // Pre-barrier: everything not involving P.
  float a0 = 0.f, a1 = 0.f, a2 = 0.f;
  float b0 = 0.f, b1 = 0.f, b2 = 0.f, b3 = 0.f, b4 = 0.f;
  if (v0) {
    a0 = dot4(R[0], R[0]) + dot4(R[1], R[1]);
    a1 = dot4(R[2], R[2]) + dot4(R[3], R[3]);
    a2 = dot4(R[0], R[2]) + dot4(R[1], R[3]);
  }
  if (v1) {
    b0 = dot4(N[0], N[0]) + dot4(N[1], N[1]);
    b1 = dot4(N[2], N[2]) + dot4(N[3], N[3]);
    b2 = dot4(N[0], N[2]) + dot4(N[1], N[3]);
  }
  if (needP1) {
    b3 = dot4(N[0], R[0]) + dot4(N[1], R[1]);  // aj[s0] logits
    b4 = dot4(N[2], R[2]) + dot4(N[3], R[3]);  // aj[s0] tgt
  }

  __syncthreads();

  float a3 = 0.f, a4 = 0.f;
  if (needP) {
    if (k != 0) {  // prev row from the previous chunk's LDS export
      P[0] = lds[wv - 2][lane];
      P[1] = lds[wv - 2][lane + 64];
      P[2] = lds[wv - 2][lane + 128];
      P[3] = lds[wv - 2][lane + 192];
    }
    a3 = dot4(R[0], P[0]) + dot4(R[1], P[1]);  // aj[s0-1] logits
    a4 = dot4(R[2], P[2]) + dot4(R[3], P[3]);  // aj[s0-1] tgt
  }

  if (v0) { a0 = red64_uni(a0); a1 = red64_uni(a1); a2 = red64_uni(a2); }
  if (needP) { a3 = red64_uni(a3); a4 = red64_uni(a4); }
  if (v1) { b0 = red64_uni(b0); b1 = red64_uni(b1); b2 = red64_uni(b2); }
  if (needP1) { b3 = red64_uni(b3); b4 = red64_uni(b4); }

  if (lane == 0) {
    const int i = b * S_DIM + s0;
    if (v0) { nl2p[2 * i + h] = a0; nt2p[2 * i + h] = a1; ltp[2 * i + h] = a2; }
    if (needP) { ajlp[2 * (i - 1) + h] = a3; ajtp[2 * (i - 1) + h] = a4; }
    if (v1) {
      const int i2 = i + 1;
      nl2p[2 * i2 + h] = b0; nt2p[2 * i2 + h] = b1; ltp[2 * i2 + h] = b2;
    }
    if (needP1) { ajlp[2 * i + h] = b3; ajtp[2 * i + h] = b4; }
  }
}

// Sum the two d-half partials with one float2 load.
__device__ __forceinline__ float ld2(const float* p, int i) {
  float2 v = reinterpret_cast<const float2*>(p)[i];
  return v.x + v.y;
}

// ---------------------------------------------------------------------------
// Kernel 2: mask-weighted row sums + pair delta/dd terms. 128 blocks x 128
// threads; ballot-built validity bitmaps make the next-valid-pair search a
// bit scan. Reads only stats entries whose validity gate passed (which
// row_stats wrote) -- never the unwritten (poisoned) ones.
// ---------------------------------------------------------------------------
__global__ __launch_bounds__(128) void pair_kernel(
    const unsigned char* __restrict__ mask, float* __restrict__ ws) {
  const float* nl2p = ws;
  const float* nt2p = ws + 2 * BS;
  const float* ltp  = ws + 4 * BS;
  const float* ajlp = ws + 6 * BS;
  const float* ajtp = ws + 8 * BS;
  float* partial = ws + 10 * BS;

  __shared__ unsigned long long vb[16];
  __shared__ float psum[6][2];
  __shared__ int s_flag;

  const int tid = threadIdx.x;
  const int w = tid >> 6, lane = tid & 63;

  if (tid == 0) s_flag = 0;
  __syncthreads();
  int any = 0;
  for (int i = tid; i < 1024; i += 128)
    if ((i & 3) == 1 && mask[i]) any = 1;
  if (any) s_flag = 1;
  __syncthreads();
  const bool isbyte = (s_flag != 0);

  int B0 = (blockIdx.x * 128) / 63;
  if (B0 > B_DIM - 16) B0 = B_DIM - 16;

#pragma unroll
  for (int k = 0; k < 8; ++k) {
    const int q = k * 2 + w;
    const int g2 = (B0 + q) * 64 + lane;
    bool val = mask[isbyte ? g2 : (g2 << 2)] == 0;
    unsigned long long bal = __ballot(val);
    if (lane == 0) vb[q] = bal;
  }
  __syncthreads();

  const int g = blockIdx.x * 128 + tid;  // row id and pair id

  float nv = 0.f, mse = 0.f, coss = 0.f, dsum = 0.f, ddsum = 0.f, cntf = 0.f;

  // Row terms.
  if (mask[isbyte ? g : (g << 2)] == 0) {
    float A = ld2(nl2p, g), Q = ld2(nt2p, g), Cc = ld2(ltp, g);
    nv = 1.f;
    mse = A + Q - 2.f * Cc;
    coss = 1.f - Cc / (fmaxf(sqrtf(A), 1e-8f) * fmaxf(sqrtf(Q), 1e-8f));
  }

  // Pair terms.
  if (g < LP) {
    const int b = g / 63;
    const int s = g - b * 63;
    const unsigned long long pbb = vb[b - B0] & (vb[b - B0] >> 1);
    if ((pbb >> s) & 1ull) {
      const int i0 = b * S_DIM + s;
      float dl = ld2(ajlp, i0) / (fmaxf(sqrtf(ld2(nl2p, i0)), 1e-6f) *
                                  fmaxf(sqrtf(ld2(nl2p, i0 + 1)), 1e-6f));
      float dt = ld2(ajtp, i0) / (fmaxf(sqrtf(ld2(nt2p, i0)), 1e-6f) *
                                  fmaxf(sqrtf(ld2(nt2p, i0 + 1)), 1e-6f));
      float wv = dl - dt;
      dsum = wv * wv;
      cntf = 1.f;

      // Next valid pair: bit scan through the LDS window.
      int bq = b, sq = -1;
      bool found = false, fellback = false;
      unsigned long long cur = pbb & (~0ull << (s + 1));
      while (true) {
        if (cur) { sq = __builtin_ctzll(cur); found = true; break; }
        ++bq;
        if (bq >= B_DIM) break;
        if (bq - B0 < 16) {
          cur = vb[bq - B0] & (vb[bq - B0] >> 1);
        } else {
          fellback = true;
          break;
        }
      }
      if (fellback) {  // correctness fallback; ~never taken for random masks
        while (bq < B_DIM && !found) {
          for (int s2 = 0; s2 < 63; ++s2) {
            int r0 = bq * S_DIM + s2;
            bool v1 = mask[isbyte ? r0 : (r0 << 2)] == 0;
            bool v2 = mask[isbyte ? (r0 + 1) : ((r0 + 1) << 2)] == 0;
            if (v1 && v2) { sq = s2; found = true; break; }
          }
          if (!found) ++bq;
        }
      }
      if (found) {
        const int j0 = bq * S_DIM + sq;
        float dlq = ld2(ajlp, j0) / (fmaxf(sqrtf(ld2(nl2p, j0)), 1e-6f) *
                                     fmaxf(sqrtf(ld2(nl2p, j0 + 1)), 1e-6f));
        float dtq = ld2(ajtp, j0) / (fmaxf(sqrtf(ld2(nt2p, j0)), 1e-6f) *
                                     fmaxf(sqrtf(ld2(nt2p, j0 + 1)), 1e-6f));
        float ddl = (dlq - dl) / ((dl != 0.f) ? dl : 1e-6f);
        float ddt = (dtq - dt) / ((dt != 0.f) ? dt : 1e-6f);
        float u = ddl - ddt;
        ddsum = u * u;
      }
    }
  }

  float vals[6] = {nv, mse, coss, dsum, ddsum, cntf};
#pragma unroll
  for (int k2 = 0; k2 < 6; ++k2) {
    float v = red64_uni(vals[k2]);
    if (lane == 0) psum[k2][w] = v;
  }
  __syncthreads();
  if (tid == 0) {
#pragma unroll
    for (int k2 = 0; k2 < 6; ++k2)
      partial[k2 * NBP + blockIdx.x] = psum[k2][0] + psum[k2][1];
  }
}

// ---------------------------------------------------------------------------
// Kernel 3: combine 128 partials into the scalar loss.
// ---------------------------------------------------------------------------
__global__ __launch_bounds__(128) void final_combine_kernel(
    const float* __restrict__ ws, float* __restrict__ out) {
  const float* partial = ws + 10 * BS;
  __shared__ float sm[6][2];
  const int tid = threadIdx.x, w = tid >> 6, lane = tid & 63;
#pragma unroll
  for (int k = 0; k < 6; ++k) {
    float v = red64_uni(partial[k * NBP + tid]);
    if (lane == 0) sm[k][w] = v;
  }
  __syncthreads();
  if (tid == 0) {
    float nv   = sm[0][0] + sm[0][1];
    float mse  = sm[1][0] + sm[1][1];
    float coss = sm[2][0] + sm[2][1];
    float dsum = sm[3][0] + sm[3][1];
    float ddsm = sm[4][0] + sm[4][1];
    float cnt  = sm[5][0] + sm[5][1];
    out[0] = mse / (nv * (float)D_DIM) + coss / nv +
             dsum / fmaxf(cnt, 1.f) + (ddsm / fmaxf(cnt - 1.f, 1.f)) * 0.01f;
  }
}

extern "C" void kernel_launch(void* const* d_in, const int* in_sizes, int n_in,
                              void* d_out, int out_size, void* d_ws, size_t ws_size,
                              hipStream_t stream) {
  const float* logits = (const float*)d_in[0];
  const float* tgt    = (const float*)d_in[1];
  const unsigned char* mask = (const unsigned char*)d_in[2];
  float* out = (float*)d_out;
  float* ws  = (float*)d_ws;

  row_stats_kernel<<<dim3(2048), dim3(512), 0, stream>>>(logits, tgt, mask, ws);
  pair_kernel<<<dim3(NBP), dim3(128), 0, stream>>>(mask, ws);
  final_combine_kernel<<<dim3(1), dim3(128), 0, stream>>>(ws, out);
}